// Round 18
// baseline (417.700 us; speedup 1.0000x reference)
//
#include <hip/hip_runtime.h>

#define NN 8
#define KK 8
#define CI 128
#define CO 128
#define HT 128
#define WT 128

// ---------------------------------------------------------------------------
// V6 ("shared-frac") semantics — hypothesized np-port idiom, all f32:
//   inv  = 1.0f / max(h-1, 1)          (f32 reciprocal)
//   frac = dy * inv                     (f32 mul)
//   uw   = frac * 127.0f                (f32 mul)   [window]
//   uc   = frac * 63.0f                 (f32 mul)   [crop]
// Ring lines (dy == h-1): frac = fl(den*fl(1/den)) in {1, 1-2^-24}.
//   frac == 1      -> uw = 127 exact -> weight 0            (ref-zero pixels)
//   frac == 1-2^-24 -> uw = 127 - 2^-17 -> weight = 2^-17 * win126(vw)
//                      <= 6.3e-7 < 1e-6  (sub-floor tiny weight)
// These flow through out = sum(w q s)/max(sum w, 1e-6) with NO special cases.
// Crop at ring: uc = 63 - 2^-18 -> effectively row 63 (literal, r8-proven).
// Literal clip semantics everywhere: u0=clip(floor(u),0,S-2), du=clip(u-u0,0,1).
// ---------------------------------------------------------------------------
__global__ __launch_bounds__(256) void k_fused(const float* __restrict__ x,
                                               const float* __restrict__ Wm,
                                               const float* __restrict__ bias,
                                               const float* __restrict__ win,
                                               const float* __restrict__ qs,
                                               const int* __restrict__ boxes,
                                               float* __restrict__ out) {
    __shared__ float Wl[CO * CI];   // W[o][c], 64 KB
    int t = threadIdx.x;
    int n = blockIdx.y;
    int Yi = blockIdx.x;

    for (int i = t; i < CO * CI; i += 256) Wl[i] = Wm[i];
    __syncthreads();

    int X = t & 127;
    int og = t >> 7;

    float xacc[CI];
    #pragma unroll
    for (int c = 0; c < CI; ++c) xacc[c] = 0.f;
    float wsum = 0.f;
    float sq = 0.f;

    for (int k = 0; k < KK; ++k) {
        const int* bp = boxes + (n * KK + k) * 4;
        int bx = bp[0], by = bp[1], bx1 = bp[2], by1 = bp[3];
        int hh = by1 - by, ww = bx1 - bx;
        int dyi = Yi - by, dxi = X - bx;
        bool mask = (dyi >= 0) && (Yi < by1) && (dxi >= 0) && (X < bx1);

        float dy = (float)dyi, dx = (float)dxi;
        float denY = fmaxf((float)hh - 1.f, 1.f);
        float denX = fmaxf((float)ww - 1.f, 1.f);
        // shared normalized fraction: rcp then two separate muls (no fma chain)
        float invY = 1.0f / denY;
        float invX = 1.0f / denX;
        float fy = dy * invY;
        float fx = dx * invX;

        float weight = 0.f;
        if (mask) {
            if (k == 0) {
                weight = 1.f;
            } else {
                float uw = fy * 127.0f;
                float vw = fx * 127.0f;
                int u0w = min(max((int)floorf(uw), 0), 126);
                int v0w = min(max((int)floorf(vw), 0), 126);
                float duw = fminf(fmaxf(uw - (float)u0w, 0.f), 1.f);
                float dvw = fminf(fmaxf(vw - (float)v0w, 0.f), 1.f);
                const float* wp = win + u0w * WT + v0w;
                float a = wp[0], b2 = wp[1], c2 = wp[WT], d2 = wp[WT + 1];
                float r_v0 = a  * (1.f - duw) + c2 * duw;   // rows (u) first
                float r_v1 = b2 * (1.f - duw) + d2 * duw;
                weight = r_v0 * (1.f - dvw) + r_v1 * dvw;
            }
        }
        wsum += weight;
        float q1 = qs[(n * KK + k) * 2 + 1];
        float wq = weight * q1;
        sq += wq;

        if (wq != 0.f) {
            float u = fy * 63.0f;
            float v = fx * 63.0f;
            int u0 = min(max((int)floorf(u), 0), 62);
            int v0 = min(max((int)floorf(v), 0), 62);
            float du = fminf(fmaxf(u - (float)u0, 0.f), 1.f);
            float dv = fminf(fmaxf(v - (float)v0, 0.f), 1.f);
            float omdu = 1.f - du, omdv = 1.f - dv;
            const float* xb = x + ((size_t)(n * KK + k) * CI) * 4096 + u0 * 64 + v0;
            #pragma unroll
            for (int c = 0; c < CI; ++c) {
                const float* p = xb + (size_t)c * 4096;
                float s = (p[0] * omdu + p[64] * du) * omdv
                        + (p[1] * omdu + p[65] * du) * dv;
                xacc[c] += wq * s;
            }
        }
    }

    float den = fmaxf(wsum, 1e-6f);
    float* ocol = out + ((size_t)n * CO) * 16384 + (size_t)Yi * 128 + X;
    for (int j = 0; j < 64; ++j) {
        int o = og * 64 + j;
        const float* wr = Wl + o * CI;
        float acc = 0.f;
        #pragma unroll
        for (int c = 0; c < CI; ++c) acc += wr[c] * xacc[c];
        ocol[(size_t)o * 16384] = (acc + bias[o] * sq) / den;
    }
}

// ---------------------------------------------------------------------------
extern "C" void kernel_launch(void* const* d_in, const int* in_sizes, int n_in,
                              void* d_out, int out_size, void* d_ws, size_t ws_size,
                              hipStream_t stream) {
    const float* x    = (const float*)d_in[0];
    const float* Wm   = (const float*)d_in[1];
    const float* bias = (const float*)d_in[2];
    const float* win  = (const float*)d_in[3];
    const float* qs   = (const float*)d_in[4];
    const int*   bxs  = (const int*)d_in[5];
    float* out = (float*)d_out;

    hipLaunchKernelGGL(k_fused, dim3(HT, NN), dim3(256), 0, stream,
                       x, Wm, bias, win, qs, bxs, out);
}

// Round 19
// 108.011 us; speedup vs baseline: 3.8672x; 3.8672x over previous
//
#include <hip/hip_runtime.h>
#include <hip/hip_fp16.h>

#define NN 8
#define KK 8
#define CI 128
#define CO 128
#define HT 128
#define WT 128

typedef __attribute__((ext_vector_type(8))) _Float16 f16x8;
typedef __attribute__((ext_vector_type(4))) float f32x4;

__device__ __forceinline__ unsigned short f2h_bits(float v) {
    _Float16 h = (_Float16)v;
    unsigned short b;
    __builtin_memcpy(&b, &h, 2);
    return b;
}
__device__ __forceinline__ float hLO(unsigned int u) {
    unsigned short b = (unsigned short)(u & 0xffffu);
    _Float16 h; __builtin_memcpy(&h, &b, 2);
    return (float)h;
}
__device__ __forceinline__ float hHI(unsigned int u) {
    unsigned short b = (unsigned short)(u >> 16);
    _Float16 h; __builtin_memcpy(&h, &b, 2);
    return (float)h;
}

// ---------------------------------------------------------------------------
// K1: 1x1 conv via fp16 MFMA.  f[b][px][o] (fp16, channel-last) =
//     sum_c x[b][c][px] * W[o][c] + bias[o]
// Fragment indexing empirically validated (rounds 2/3: MFMA == VALU conv).
// ---------------------------------------------------------------------------
__global__ __launch_bounds__(256) void k_conv(const float* __restrict__ x,
                                              const float* __restrict__ Wm,
                                              const float* __restrict__ bias,
                                              unsigned short* __restrict__ f) {
    __shared__ unsigned char lds[65536];   // A: [128px][128c] f16 swz ; B at +32768
    int t = threadIdx.x;
    int b = blockIdx.y;
    int px0 = blockIdx.x * 128;
    const float* xb = x + (size_t)b * CI * 4096;

    // stage A (transpose: global [c][px] -> LDS [px][c], fp16)
    #pragma unroll
    for (int p = 0; p < 8; ++p) {
        int px = (t & 63) + 64 * (p & 1);
        int c0 = 8 * ((t >> 6) + 4 * (p >> 1));
        unsigned int v0w, v1w, v2w, v3w;
        {
            unsigned short s0 = f2h_bits(xb[(size_t)(c0 + 0) * 4096 + px0 + px]);
            unsigned short s1 = f2h_bits(xb[(size_t)(c0 + 1) * 4096 + px0 + px]);
            unsigned short s2 = f2h_bits(xb[(size_t)(c0 + 2) * 4096 + px0 + px]);
            unsigned short s3 = f2h_bits(xb[(size_t)(c0 + 3) * 4096 + px0 + px]);
            unsigned short s4 = f2h_bits(xb[(size_t)(c0 + 4) * 4096 + px0 + px]);
            unsigned short s5 = f2h_bits(xb[(size_t)(c0 + 5) * 4096 + px0 + px]);
            unsigned short s6 = f2h_bits(xb[(size_t)(c0 + 6) * 4096 + px0 + px]);
            unsigned short s7 = f2h_bits(xb[(size_t)(c0 + 7) * 4096 + px0 + px]);
            v0w = (unsigned int)s0 | ((unsigned int)s1 << 16);
            v1w = (unsigned int)s2 | ((unsigned int)s3 << 16);
            v2w = (unsigned int)s4 | ((unsigned int)s5 << 16);
            v3w = (unsigned int)s6 | ((unsigned int)s7 << 16);
        }
        int L = px * 256 + c0 * 2;
        L ^= ((px & 15) << 4);
        uint4 pk; pk.x = v0w; pk.y = v1w; pk.z = v2w; pk.w = v3w;
        *(uint4*)(lds + L) = pk;
    }
    // stage B (W is [o][c] row-major, fp16)
    #pragma unroll
    for (int p = 0; p < 16; ++p) {
        int o = (t >> 5) + 8 * p;
        int c0 = (t & 31) * 4;
        float4 wv = *(const float4*)(Wm + o * CI + c0);
        unsigned int w0 = (unsigned int)f2h_bits(wv.x) | ((unsigned int)f2h_bits(wv.y) << 16);
        unsigned int w1 = (unsigned int)f2h_bits(wv.z) | ((unsigned int)f2h_bits(wv.w) << 16);
        int L = 32768 + o * 256 + c0 * 2;
        L ^= ((o & 15) << 4);
        uint2 pk; pk.x = w0; pk.y = w1;
        *(uint2*)(lds + L) = pk;
    }
    __syncthreads();

    int wid = t >> 6;
    int l   = t & 63;
    int lr  = l & 15;
    int lk  = l >> 4;

    f32x4 acc[2][8];
    #pragma unroll
    for (int m = 0; m < 2; ++m)
        #pragma unroll
        for (int j = 0; j < 8; ++j)
            acc[m][j] = (f32x4){0.f, 0.f, 0.f, 0.f};

    #pragma unroll
    for (int s = 0; s < 4; ++s) {
        int c = s * 32 + lk * 8;
        f16x8 afr[2], bfr[8];
        #pragma unroll
        for (int m = 0; m < 2; ++m) {
            int px = wid * 32 + m * 16 + lr;
            int L = px * 256 + c * 2;
            L ^= ((px & 15) << 4);
            afr[m] = *(const f16x8*)(lds + L);
        }
        #pragma unroll
        for (int j = 0; j < 8; ++j) {
            int o = j * 16 + lr;
            int L = 32768 + o * 256 + c * 2;
            L ^= ((o & 15) << 4);
            bfr[j] = *(const f16x8*)(lds + L);
        }
        #pragma unroll
        for (int m = 0; m < 2; ++m)
            #pragma unroll
            for (int j = 0; j < 8; ++j)
                acc[m][j] = __builtin_amdgcn_mfma_f32_16x16x32_f16(afr[m], bfr[j], acc[m][j], 0, 0, 0);
    }

    float bs[8];
    #pragma unroll
    for (int j = 0; j < 8; ++j) bs[j] = bias[j * 16 + lr];
    #pragma unroll
    for (int m = 0; m < 2; ++m) {
        int pxb = px0 + wid * 32 + m * 16 + lk * 4;
        #pragma unroll
        for (int j = 0; j < 8; ++j) {
            int o = j * 16 + lr;
            #pragma unroll
            for (int r = 0; r < 4; ++r) {
                float v = acc[m][j][r] + bs[j];
                f[((size_t)b * 4096 + (pxb + r)) * CO + o] = f2h_bits(v);
            }
        }
    }
}

// ---------------------------------------------------------------------------
// K2: per-thread sampler with V6 (shared-frac f32) coordinates — the
// PROVEN-passing semantics from round 18:
//   inv = 1/max(den,1); fy = dy*inv; uw = fy*127 (window), uc = fy*63 (crop)
// Corners read from channel-last fp16 f: 4 x 256B contiguous.
// Thread (X = t&127, og = t>>7) owns channels og*64..og*64+63 of (Yi, X).
// ---------------------------------------------------------------------------
__global__ __launch_bounds__(256) void k_sample(const unsigned short* __restrict__ f,
                                                const float* __restrict__ win,
                                                const float* __restrict__ qs,
                                                const int* __restrict__ boxes,
                                                float* __restrict__ out) {
    int t = threadIdx.x;
    int n = blockIdx.y;
    int Yi = blockIdx.x;
    int X = t & 127;
    int og = t >> 7;

    float acc[64];
    #pragma unroll
    for (int i = 0; i < 64; ++i) acc[i] = 0.f;
    float wsum = 0.f;

    for (int k = 0; k < KK; ++k) {
        const int* bp = boxes + (n * KK + k) * 4;
        int bx = bp[0], by = bp[1], bx1 = bp[2], by1 = bp[3];
        int hh = by1 - by, ww = bx1 - bx;
        int dyi = Yi - by, dxi = X - bx;
        bool mask = (dyi >= 0) && (Yi < by1) && (dxi >= 0) && (X < bx1);

        float dy = (float)dyi, dx = (float)dxi;
        float denY = fmaxf((float)hh - 1.f, 1.f);
        float denX = fmaxf((float)ww - 1.f, 1.f);
        float invY = 1.0f / denY;
        float invX = 1.0f / denX;
        float fy = dy * invY;
        float fx = dx * invX;

        float weight = 0.f;
        if (mask) {
            if (k == 0) {
                weight = 1.f;
            } else {
                float uw = fy * 127.0f;
                float vw = fx * 127.0f;
                int u0w = min(max((int)floorf(uw), 0), 126);
                int v0w = min(max((int)floorf(vw), 0), 126);
                float duw = fminf(fmaxf(uw - (float)u0w, 0.f), 1.f);
                float dvw = fminf(fmaxf(vw - (float)v0w, 0.f), 1.f);
                const float* wp = win + u0w * WT + v0w;
                float a = wp[0], b2 = wp[1], c2 = wp[WT], d2 = wp[WT + 1];
                float r_v0 = a  * (1.f - duw) + c2 * duw;
                float r_v1 = b2 * (1.f - duw) + d2 * duw;
                weight = r_v0 * (1.f - dvw) + r_v1 * dvw;
            }
        }
        wsum += weight;
        float q1 = qs[(n * KK + k) * 2 + 1];
        float wk = weight * q1;

        if (wk != 0.f) {
            float u = fy * 63.0f;
            float v = fx * 63.0f;
            int u0 = min(max((int)floorf(u), 0), 62);
            int v0 = min(max((int)floorf(v), 0), 62);
            float du = fminf(fmaxf(u - (float)u0, 0.f), 1.f);
            float dv = fminf(fmaxf(v - (float)v0, 0.f), 1.f);
            float w11 = du * dv * wk;
            float w10 = du * (1.f - dv) * wk;
            float w01 = (1.f - du) * dv * wk;
            float w00 = (1.f - du) * (1.f - dv) * wk;
            const unsigned short* pA =
                f + ((size_t)((n * KK + k) * 4096 + u0 * 64 + v0)) * CO + og * 64;
            #pragma unroll
            for (int ch = 0; ch < 8; ++ch) {
                uint4 A = *(const uint4*)(pA + ch * 8);                 // (u0,   v0)
                uint4 B = *(const uint4*)(pA + CO + ch * 8);            // (u0,   v0+1)
                uint4 C = *(const uint4*)(pA + 64 * CO + ch * 8);       // (u0+1, v0)
                uint4 D = *(const uint4*)(pA + 65 * CO + ch * 8);       // (u0+1, v0+1)
#define DO_PAIR(ae, be, ce, de, o0)                                             \
                acc[o0]     += w00 * hLO(ae) + w01 * hLO(be)                    \
                             + w10 * hLO(ce) + w11 * hLO(de);                   \
                acc[(o0)+1] += w00 * hHI(ae) + w01 * hHI(be)                    \
                             + w10 * hHI(ce) + w11 * hHI(de);
                DO_PAIR(A.x, B.x, C.x, D.x, ch * 8 + 0)
                DO_PAIR(A.y, B.y, C.y, D.y, ch * 8 + 2)
                DO_PAIR(A.z, B.z, C.z, D.z, ch * 8 + 4)
                DO_PAIR(A.w, B.w, C.w, D.w, ch * 8 + 6)
#undef DO_PAIR
            }
        }
    }

    float den = fmaxf(wsum, 1e-6f);
    float id = 1.f / den;
    #pragma unroll
    for (int i = 0; i < 64; ++i) {
        int o = og * 64 + i;
        out[((size_t)n * CO + o) * 16384 + Yi * 128 + X] = acc[i] * id;
    }
}

// ---------------------------------------------------------------------------
extern "C" void kernel_launch(void* const* d_in, const int* in_sizes, int n_in,
                              void* d_out, int out_size, void* d_ws, size_t ws_size,
                              hipStream_t stream) {
    const float* x    = (const float*)d_in[0];
    const float* Wm   = (const float*)d_in[1];
    const float* bias = (const float*)d_in[2];
    const float* win  = (const float*)d_in[3];
    const float* qs   = (const float*)d_in[4];
    const int*   bxs  = (const int*)d_in[5];
    float* out = (float*)d_out;

    unsigned short* f = (unsigned short*)d_ws;   // 64*4096*128 fp16 = 64 MiB

    hipLaunchKernelGGL(k_conv,   dim3(32, 64), dim3(256), 0, stream, x, Wm, bias, f);
    hipLaunchKernelGGL(k_sample, dim3(128, 8), dim3(256), 0, stream, f, win, qs, bxs, out);
}